// Round 18
// baseline (334.531 us; speedup 1.0000x reference)
//
#include <hip/hip_runtime.h>

#define NA      30000
#define MPAD    30080            // 235 * 128
#define NPAIRS  1200000
#define NB      7
#define NK      5
#define NSP     119
#define NFEAT   360
#define KP1     384              // NFEAT padded to 64
#define NU      512
#define WROW    36               // padded W row (35 -> 36 floats, 144B, 16B aligned)
#define MAXSLOT 120              // plist slots per atom (Poisson(40): P(deg>120) ~ 0)
#define PSTRIDE 128              // plist row stride in ints (alignment)
#define NBK     118              // coarse buckets of 256 atoms (ceil(30000/256))
#define BCAP    11520            // entries per coarse bucket (mean 10240, sd ~101)
#define PPB     4688             // pairs per partition block (256 blocks)
#define NTILE   235              // 128-atom tiles

#define BETTA      1.3611111111111112f     // 49/36
#define RADNORM    0.96481348f             // (2*betta/pi)^0.25
#define SHIFT_STEP 0.7857142857142857f     // 5.5/7
#define PI_OVER_R  0.5235987755982988f     // pi/6
#define INV_SQRT7  0.3779644730092272f
#define RMAXV      6.0f

typedef __attribute__((ext_vector_type(8))) short bf16x8;
typedef __attribute__((ext_vector_type(4))) float f32x4;
typedef __attribute__((ext_vector_type(2))) float f32x2;

__device__ __forceinline__ unsigned short f2b(float x) {
    unsigned u = __float_as_uint(x);
    unsigned r = u + 0x7FFF + ((u >> 16) & 1);   // RNE (inputs are finite)
    return (unsigned short)(r >> 16);
}

// ---------------- phase 1: partition pairs into 118 coarse buckets ----------------
// entry pack: (i&255)<<22 | Zj<<15 | j   (iloc 8b, Zj 7b, j 15b)
__global__ __launch_bounds__(256)
void k_part(const int* __restrict__ idx, const int* __restrict__ Z,
            int* __restrict__ gcur, int* __restrict__ part) {
    __shared__ int hist[NBK];
    __shared__ int base[NBK];
    int tid = threadIdx.x;
    for (int b = tid; b < NBK; b += 256) hist[b] = 0;
    __syncthreads();
    int p0 = blockIdx.x * PPB;
    int p1 = min(p0 + PPB, NPAIRS);
    for (int p = p0 + tid; p < p1; p += 256)
        atomicAdd(&hist[idx[p] >> 8], 1);
    __syncthreads();
    for (int b = tid; b < NBK; b += 256) {
        base[b] = atomicAdd(&gcur[b], hist[b]);
        hist[b] = 0;
    }
    __syncthreads();
    for (int p = p0 + tid; p < p1; p += 256) {
        int i = idx[p];
        int b = i >> 8;
        int j = idx[NPAIRS + p];
        int zj = Z[j];
        int off = base[b] + atomicAdd(&hist[b], 1);
        if (off < BCAP)
            part[b * BCAP + off] = ((i & 255) << 22) | (zj << 15) | j;
    }
}

// ---------------- phase 2: coarse buckets -> dense CSR rows (coalesced writes) ----
__global__ __launch_bounds__(256)
void k_csr(const int* __restrict__ part, const int* __restrict__ gcnt,
           int* __restrict__ counts, int* __restrict__ plist) {
    __shared__ int lp[128 * MAXSLOT];   // 61440 B
    __shared__ int lc[128];
    int tid = threadIdx.x;
    int lane = tid & 63, wave = tid >> 6;
    int w = blockIdx.x;                 // 128-atom window, 0..234
    int cb = w >> 1;                    // coarse bucket
    int par = w & 1;                    // which 128-half of the 256-atom bucket
    for (int t = tid; t < 128; t += 256) lc[t] = 0;
    __syncthreads();
    int n = min(gcnt[cb], BCAP);
    for (int e = tid; e < n; e += 256) {
        int v = part[cb * BCAP + e];
        int iloc = v >> 22;             // 0..255
        if ((iloc >> 7) == par) {
            int i7 = iloc & 127;
            int r = atomicAdd(&lc[i7], 1);
            if (r < MAXSLOT) lp[i7 * MAXSLOT + r] = v & 0x3FFFFF;  // Zj<<15 | j
        }
    }
    __syncthreads();
    for (int t = tid; t < 128; t += 256) {
        int a = w * 128 + t;
        if (a < NA) counts[a] = min(lc[t], MAXSLOT);
    }
    // coalesced row writes: each wave 32 rows (4 waves x 32 = 128 rows)
    for (int rr = 0; rr < 32; rr++) {
        int row = wave * 32 + rr;
        int a = w * 128 + row;
        if (a < NA) {
            for (int c = lane; c < MAXSLOT; c += 64)
                plist[(size_t)a * PSTRIDE + c] = lp[row * MAXSLOT + c];
        }
    }
}

// ------- merged prep (runs FIRST): zero gcur/tileCnt + d_out, pad W/R, transpose --
#define PREP_W   (NSP*NSP*WROW)          // 509796
#define PREP_R   NA                      // 30000
#define PREP_W1  (NU*KP1)                // 196608
#define PREP_W2  (NU*NU)                 // 262144
#define PREP_TOT (PREP_W + PREP_R + PREP_W1 + PREP_W2)
__global__ void k_prep(const float* __restrict__ W, const float* __restrict__ R,
                       const float* __restrict__ w1, const float* __restrict__ w2,
                       float* __restrict__ Wp, float* __restrict__ Rp,
                       unsigned short* __restrict__ w1T, unsigned short* __restrict__ w2T,
                       int* __restrict__ gcur, float* __restrict__ out) {
    int i = blockIdx.x * blockDim.x + threadIdx.x;
    if (i < 512) gcur[i] = 0;            // bucket cursors [0..117] + tileCnt [128..362]
    if (i < NA) out[i] = 0.f;            // layer-3 accumulator
    if (i < PREP_W) {
        int row = i / WROW, e = i - row * WROW;
        Wp[i] = (e < NK * NB) ? W[row * (NK * NB) + e] : 0.f;
        return;
    }
    i -= PREP_W;
    if (i < PREP_R) {
        f32x4 v = {R[3*i], R[3*i+1], R[3*i+2], 0.f};
        *(f32x4*)&Rp[4*i] = v;
        return;
    }
    i -= PREP_R;
    if (i < PREP_W1) {
        int c = i / KP1, kp = i - c * KP1;
        w1T[i] = (kp < NFEAT) ? f2b(w1[kp * NU + c]) : (unsigned short)0;
        return;
    }
    i -= PREP_W1;
    if (i < PREP_W2) {
        int c = i >> 9, kp = i & 511;
        w2T[i] = f2b(w2[kp * NU + c]);
    }
}

// ------- fused moments + contraction: 512 threads = 64 atoms x 8 lanes -----------
// Phase A (all 8 waves): pk-fp32 moment accumulation, 8 lanes/atom, butterfly
//   reduce, lane q==0 writes MS[100][65] LDS.
// Phase B: contraction split across ALL 8 WAVES (R17 used 4 -> unbalanced;
//   w0: m0+c1+c2+c3, w1: c4 r=0, w2: c4 r>=1, w3: c5, w4/w5: c6, w6/w7: c7+pad),
//   all 64 lanes active per wave (lane = atom).
// NOTE 1 (R8): min-waves stays 2 — pinning 4 caps VGPRs at 128, spills acc (5x).
// NOTE 2 (R9): acc[] only with compile-time indices (runtime idx -> scratch).
// NOTE 3 (R10/R15): 8 lanes/atom is the TLP sweet spot (2x8 split: 64us;
//   16-wide: 61us via residency-cap rounds + unamortized epilogue).
__global__ __launch_bounds__(512, 2)
void k_momcon(const float* __restrict__ Rp, const int* __restrict__ Z,
              const float* __restrict__ Wp, const int* __restrict__ counts,
              const int* __restrict__ plist, unsigned short* __restrict__ gmB) {
    __shared__ float MS[100 * 65];      // 26000 B
    int tid = threadIdx.x;
    int g = tid >> 3, q = tid & 7;      // local atom 0..63, lane-in-group
    int a0 = blockIdx.x * 64;
    int a = a0 + g;

    if (a < NA) {
        f32x4 ri = *(const f32x4*)&Rp[4*a];
        int Zi = Z[a];
        f32x2 acc[50];
#pragma unroll
        for (int u = 0; u < 50; u++) acc[u] = (f32x2){0.f, 0.f};
        int cnt = min(counts[a], MAXSLOT);
        const int* prow = plist + (size_t)a * PSTRIDE;

        for (int t = q; t < cnt; t += 8) {
            int pk = prow[t];
            int j  = pk & 0x7FFF;
            int Zj = (pk >> 15) & 0x7F;
            f32x4 rj = *(const f32x4*)&Rp[4*j];

            const f32x4* wrow = (const f32x4*)&Wp[(Zi * NSP + Zj) * WROW];
            f32x4 w4[9];
#pragma unroll
            for (int c = 0; c < 9; c++) w4[c] = wrow[c];
            const float* wf = (const float*)w4;

            float dx = rj.x - ri.x, dy = rj.y - ri.y, dz = rj.z - ri.z;
            float d2 = dx*dx + dy*dy + dz*dz + 1e-12f;
            float dr = sqrtf(d2);
            float inv = 1.0f / (dr + 1e-5f);
            float nx = dx*inv, ny = dy*inv, nz = dz*inv;

            float basis[NB];
#pragma unroll
            for (int b = 0; b < NB; b++) {
                float tt = dr - (0.5f + SHIFT_STEP * (float)b);
                basis[b] = RADNORM * __expf(-BETTA * tt * tt);
            }
            float cut = (dr < RMAXV) ? 0.5f * (__cosf(PI_OVER_R * dr) + 1.0f) : 0.0f;
            cut *= INV_SQRT7;
            float rad[NK];
#pragma unroll
            for (int k = 0; k < NK; k++) {
                float s = 0.f;
#pragma unroll
                for (int b = 0; b < NB; b++) s += wf[k*NB + b] * basis[b];
                rad[k] = s * cut;
            }
            float gg[20];
            gg[0] = 1.f; gg[1] = nx; gg[2] = ny; gg[3] = nz;
            gg[4] = nx*nx; gg[5] = nx*ny; gg[6] = nx*nz; gg[7] = ny*ny; gg[8] = ny*nz; gg[9] = nz*nz;
            gg[10] = gg[4]*nx; gg[11] = gg[4]*ny; gg[12] = gg[4]*nz; gg[13] = gg[5]*ny; gg[14] = gg[5]*nz;
            gg[15] = gg[6]*nz; gg[16] = gg[7]*ny; gg[17] = gg[7]*nz; gg[18] = gg[8]*nz; gg[19] = gg[9]*nz;
            f32x2 g2[10];
#pragma unroll
            for (int u = 0; u < 10; u++) g2[u] = (f32x2){gg[2*u], gg[2*u+1]};
#pragma unroll
            for (int k = 0; k < NK; k++) {
                f32x2 rk = (f32x2){rad[k], rad[k]};
#pragma unroll
                for (int u = 0; u < 10; u++)
                    acc[k*10 + u] += rk * g2[u];      // v_pk_fma_f32
            }
        }
        // reduce within the 8-lane group as 64-bit packets
#pragma unroll
        for (int u = 0; u < 50; u++) {
            f32x2 v = acc[u];
            double d = __builtin_bit_cast(double, v);
            d = __shfl_xor(d, 1);
            v += __builtin_bit_cast(f32x2, d);
            d = __builtin_bit_cast(double, v);
            d = __shfl_xor(d, 2);
            v += __builtin_bit_cast(f32x2, d);
            d = __builtin_bit_cast(double, v);
            d = __shfl_xor(d, 4);
            v += __builtin_bit_cast(f32x2, d);
            acc[u] = v;
        }
        if (q == 0) {
#pragma unroll
            for (int u = 0; u < 50; u++) {
                MS[(2*u)     * 65 + g] = acc[u].x;
                MS[(2*u + 1) * 65 + g] = acc[u].y;
            }
        }
    }
    __syncthreads();

    // ---- phase B: contraction, 8 waves split feature groups, lane = atom ----
    int lane = tid & 63, wave = tid >> 6;
    int aB = a0 + lane;
    bool ok = (aB < NA);
    const int S2[3][3] = {{0,1,2},{1,3,4},{2,4,5}};
    const int S3[3][3][3] = {
        {{0,1,2},{1,3,4},{2,4,5}},
        {{1,3,4},{3,6,7},{4,7,8}},
        {{2,4,5},{4,7,8},{5,8,9}}
    };
    unsigned short* row = gmB + (size_t)aB * KP1;
#define LD(comp) MS[(comp) * 65 + lane]

    if (wave == 0) {
        // m0 (f0..4), c1 (5..19), c2 (20..34), c3 (35..49)
        if (ok) {
            for (int k = 0; k < 5; k++) row[k] = f2b(LD(k * 20));
        }
        int f = 5;
        for (int r = 0; r < 5; r++)
            for (int s = r; s < 5; s++) {
                float v = 0.f;
#pragma unroll
                for (int i = 0; i < 3; i++) v += LD(r*20+1+i) * LD(s*20+1+i);
                if (ok) row[f] = f2b(v);
                f++;
            }
        const float W2U[6] = {1,2,2,1,2,1};
        for (int r = 0; r < 5; r++)
            for (int s = r; s < 5; s++) {
                float v = 0.f;
#pragma unroll
                for (int u = 0; u < 6; u++) v += W2U[u] * LD(r*20+4+u) * LD(s*20+4+u);
                if (ok) row[f] = f2b(v);
                f++;
            }
        const float W3U[10] = {1,3,3,3,6,3,1,3,3,1};
        for (int r = 0; r < 5; r++)
            for (int s = r; s < 5; s++) {
                float v = 0.f;
#pragma unroll
                for (int u = 0; u < 10; u++) v += W3U[u] * LD(r*20+10+u) * LD(s*20+10+u);
                if (ok) row[f] = f2b(v);
                f++;
            }
    } else if (wave == 1 || wave == 2) {
        // c4: wave1 r=0 (f 50..64), wave2 r=1..4 (f 65..84)
        int rbeg = (wave == 1) ? 0 : 1;
        int rend = (wave == 1) ? 1 : 5;
        int f = (wave == 1) ? 50 : 65;
        for (int r = rbeg; r < rend; r++) {
            float m2r[6];
#pragma unroll
            for (int u = 0; u < 6; u++) m2r[u] = LD(r*20+4+u);
            for (int s = r; s < 5; s++) {
                float m2q[6];
#pragma unroll
                for (int u = 0; u < 6; u++) m2q[u] = LD(s*20+4+u);
                for (int t = s; t < 5; t++) {
                    float m2t[6];
#pragma unroll
                    for (int u = 0; u < 6; u++) m2t[u] = LD(t*20+4+u);
                    float v = 0.f;
#pragma unroll
                    for (int i = 0; i < 3; i++)
#pragma unroll
                        for (int j = 0; j < 3; j++)
#pragma unroll
                            for (int k = 0; k < 3; k++)
                                v += m2r[S2[i][j]] * m2q[S2[i][k]] * m2t[S2[j][k]];
                    if (ok) row[f] = f2b(v);
                    f++;
                }
            }
        }
    } else if (wave == 3) {
        // c5 (f 85..159)
        int f = 85;
        for (int r = 0; r < 5; r++) {
            float m1r[3];
#pragma unroll
            for (int i = 0; i < 3; i++) m1r[i] = LD(r*20+1+i);
            for (int s = r; s < 5; s++) {
                float m1q[3];
#pragma unroll
                for (int i = 0; i < 3; i++) m1q[i] = LD(s*20+1+i);
                for (int t = 0; t < 5; t++) {
                    float m2t[6];
#pragma unroll
                    for (int u = 0; u < 6; u++) m2t[u] = LD(t*20+4+u);
                    float v = 0.f;
#pragma unroll
                    for (int i = 0; i < 3; i++)
#pragma unroll
                        for (int j = 0; j < 3; j++)
                            v += m1r[i] * m1q[j] * m2t[S2[i][j]];
                    if (ok) row[f] = f2b(v);
                    f++;
                }
            }
        }
    } else if (wave == 4 || wave == 5) {
        // c6 (f 160..234): wave4 pairs 0..6, wave5 pairs 7..14
        int pbeg = (wave == 4) ? 0 : 7;
        int pend = (wave == 4) ? 7 : 15;
        int p = 0;
        for (int r = 0; r < 5; r++)
            for (int s = r; s < 5; s++) {
                if (p >= pbeg && p < pend) {
                    float m3r[10], m3q[10];
#pragma unroll
                    for (int u = 0; u < 10; u++) m3r[u] = LD(r*20+10+u);
#pragma unroll
                    for (int u = 0; u < 10; u++) m3q[u] = LD(s*20+10+u);
                    float T[3][3];
#pragma unroll
                    for (int k = 0; k < 3; k++)
#pragma unroll
                        for (int l = 0; l < 3; l++) {
                            float v = 0.f;
#pragma unroll
                            for (int i = 0; i < 3; i++)
#pragma unroll
                                for (int j = 0; j < 3; j++)
                                    v += m3r[S3[i][j][k]] * m3q[S3[i][j][l]];
                            T[k][l] = v;
                        }
                    int f = 160 + p * 5;
                    for (int t = 0; t < 5; t++) {
                        float m2t[6];
#pragma unroll
                        for (int u = 0; u < 6; u++) m2t[u] = LD(t*20+4+u);
                        float v = 0.f;
#pragma unroll
                        for (int k = 0; k < 3; k++)
#pragma unroll
                            for (int l = 0; l < 3; l++)
                                v += T[k][l] * m2t[S2[k][l]];
                        if (ok) row[f + t] = f2b(v);
                    }
                }
                p++;
            }
    } else {
        // c7 (f 235..359): wave6 r=0..1, wave7 r=2..4 + zero-pad
        int rbeg = (wave == 6) ? 0 : 2;
        int rend = (wave == 6) ? 2 : 5;
        for (int r = rbeg; r < rend; r++) {
            float m3r[10];
#pragma unroll
            for (int u = 0; u < 10; u++) m3r[u] = LD(r*20+10+u);
            for (int s = 0; s < 5; s++) {
                float m2q[6];
#pragma unroll
                for (int u = 0; u < 6; u++) m2q[u] = LD(s*20+4+u);
                float U0 = 0.f, U1 = 0.f, U2 = 0.f;
#pragma unroll
                for (int i = 0; i < 3; i++)
#pragma unroll
                    for (int j = 0; j < 3; j++) {
                        float ww = m2q[S2[i][j]];
                        U0 += m3r[S3[i][j][0]] * ww;
                        U1 += m3r[S3[i][j][1]] * ww;
                        U2 += m3r[S3[i][j][2]] * ww;
                    }
                int f = 235 + (r * 5 + s) * 5;
                for (int t = 0; t < 5; t++) {
                    float v = U0 * LD(t*20+1) + U1 * LD(t*20+2) + U2 * LD(t*20+3);
                    if (ok) row[f + t] = f2b(v);
                }
            }
        }
        if (wave == 7 && ok) {
            for (int z = NFEAT; z < KP1; z++) row[z] = 0;
        }
    }
#undef LD
}

// ---------------- MFMA GEMM, persistent 2 atom-tiles per block -------------------
// MODE 1: A=atoms(gmB), B=units(w1T); h1B bf16 [MPAD][512] = swish(D + bias[col]),
//         written via LDS-staged coalesced stores.
// MODE 2: A=units(w2T), B=atoms(h1B); fused layer-3 (atomicAdd w3[c]*swish(..)) AND
//         fused finish: the last of the 4 x-blocks per atom-tile (via tileCnt
//         counter, fence->barrier->atomic pattern) re-reads out[] with a coherent
//         atomic load and applies scale[Z]*(v+b3)+shift[Z].
__device__ __forceinline__ void stage8(const unsigned short* gp, unsigned short* lp) {
    __builtin_amdgcn_global_load_lds(
        (const __attribute__((address_space(1))) unsigned int*)gp,
        (__attribute__((address_space(3))) unsigned int*)lp, 16, 0, 0);
}

template<int KPAD, int MODE>
__global__ __launch_bounds__(256) void k_mfma(const unsigned short* __restrict__ A,
                                              const unsigned short* __restrict__ B,
                                              const float* __restrict__ bias,
                                              const float* __restrict__ w3,
                                              void* __restrict__ outp,
                                              const int* __restrict__ Zc,
                                              const float* __restrict__ scl,
                                              const float* __restrict__ shf,
                                              const float* __restrict__ b3p,
                                              int* __restrict__ tcnt) {
    // SMEM union: [As 16KB | Bs 16KB | red 1KB]  or  [Ot 128x136 shorts = 34816B]
    __shared__ __align__(16) unsigned char SMEM[35072];
    __shared__ int lastF;
    unsigned short* As = (unsigned short*)SMEM;
    unsigned short* Bs = (unsigned short*)(SMEM + 16384);
    float* red = (float*)(SMEM + 32768);       // [2][2][4][16]
    int tid = threadIdx.x;
    int lane = tid & 63, wave = tid >> 6;
    int wm = wave >> 1, wn = wave & 1;
    int quad = lane >> 4, l16 = lane & 15;
    int lrow = lane >> 3;          // 0..7
    int lchk = lane & 7;           // 16B chunk slot

    for (int t = 0; t < 2; t++) {
        int atile = blockIdx.y * 2 + t;
        if (atile >= NTILE) break;
        int rowA0, rowB0;
        if (MODE == 1) { rowA0 = atile * 128;      rowB0 = blockIdx.x * 128; }
        else           { rowA0 = blockIdx.x * 128; rowB0 = atile * 128; }

        f32x4 acc[4][4];
        f32x4 zero = {0.f, 0.f, 0.f, 0.f};
#pragma unroll
        for (int i = 0; i < 4; i++)
#pragma unroll
            for (int j = 0; j < 4; j++) acc[i][j] = zero;

        for (int k0 = 0; k0 < KPAD; k0 += 64) {
            __syncthreads();
#pragma unroll
            for (int i = 0; i < 4; i++) {
                int r = wave * 32 + i * 8 + lrow;
                int gc = lchk ^ (r & 7);
                stage8(A + (size_t)(rowA0 + r) * KPAD + k0 + gc * 8, &As[(wave * 32 + i * 8) * 64]);
            }
#pragma unroll
            for (int i = 0; i < 4; i++) {
                int r = wave * 32 + i * 8 + lrow;
                int gc = lchk ^ (r & 7);
                stage8(B + (size_t)(rowB0 + r) * KPAD + k0 + gc * 8, &Bs[(wave * 32 + i * 8) * 64]);
            }
            __syncthreads();
#pragma unroll
            for (int s = 0; s < 2; s++) {
                bf16x8 af[4], bfr[4];
#pragma unroll
                for (int mt = 0; mt < 4; mt++) {
                    int r = wm * 64 + mt * 16 + l16;
                    af[mt] = *(const bf16x8*)&As[r * 64 + (((s * 4 + quad) ^ (r & 7)) * 8)];
                }
#pragma unroll
                for (int nt = 0; nt < 4; nt++) {
                    int r = wn * 64 + nt * 16 + l16;
                    bfr[nt] = *(const bf16x8*)&Bs[r * 64 + (((s * 4 + quad) ^ (r & 7)) * 8)];
                }
#pragma unroll
                for (int mt = 0; mt < 4; mt++)
#pragma unroll
                    for (int nt = 0; nt < 4; nt++)
                        acc[mt][nt] = __builtin_amdgcn_mfma_f32_16x16x32_bf16(
                            af[mt], bfr[nt], acc[mt][nt], 0, 0, 0);
            }
        }

        if (MODE == 1) {
            // stage swish output tile in LDS (stride 136 shorts), then coalesced store
            __syncthreads();   // all waves done reading As/Bs
            unsigned short* Ot = (unsigned short*)SMEM;
#pragma unroll
            for (int nt = 0; nt < 4; nt++) {
                int c_loc = wn * 64 + nt * 16 + l16;
                float b = bias[rowB0 + c_loc];
#pragma unroll
                for (int mt = 0; mt < 4; mt++) {
#pragma unroll
                    for (int reg = 0; reg < 4; reg++) {
                        int a_loc = wm * 64 + mt * 16 + quad * 4 + reg;
                        float v = acc[mt][nt][reg] + b;
                        Ot[a_loc * 136 + c_loc] = f2b(v / (1.f + __expf(-v)));
                    }
                }
            }
            __syncthreads();
            unsigned short* O = (unsigned short*)outp;
            int half = lane >> 5, l32 = lane & 31;
#pragma unroll
            for (int it = 0; it < 16; it++) {
                int rloc = wave * 32 + it * 2 + half;
                int a = rowA0 + rloc;
                unsigned long long d = *(const unsigned long long*)&Ot[rloc * 136 + l32 * 4];
                if (a < NA)
                    *(unsigned long long*)&O[(size_t)a * NU + rowB0 + l32 * 4] = d;
            }
        } else {
            // fused layer-3 partial dot: per-lane over its 16 c's, quad + wm reduce
            float pn[4] = {0.f, 0.f, 0.f, 0.f};
#pragma unroll
            for (int mt = 0; mt < 4; mt++) {
#pragma unroll
                for (int reg = 0; reg < 4; reg++) {
                    int c = rowA0 + wm * 64 + mt * 16 + quad * 4 + reg;
                    float b = bias[c];
                    float w3c = w3[c];
#pragma unroll
                    for (int nt = 0; nt < 4; nt++) {
                        float v = acc[mt][nt][reg] + b;
                        pn[nt] += w3c * (v / (1.f + __expf(-v)));
                    }
                }
            }
#pragma unroll
            for (int nt = 0; nt < 4; nt++) {
                pn[nt] += __shfl_xor(pn[nt], 16);
                pn[nt] += __shfl_xor(pn[nt], 32);
            }
            __syncthreads();   // As/Bs done; red region safe vs previous tile
            if (quad == 0) {
#pragma unroll
                for (int nt = 0; nt < 4; nt++)
                    red[((wm * 2 + wn) * 4 + nt) * 16 + l16] = pn[nt];
            }
            __syncthreads();
            if (tid < 128) {
                int wn2 = tid >> 6, nt2 = (tid >> 4) & 3, lb = tid & 15;
                float s = red[((0 * 2 + wn2) * 4 + nt2) * 16 + lb]
                        + red[((1 * 2 + wn2) * 4 + nt2) * 16 + lb];
                int a = rowB0 + wn2 * 64 + nt2 * 16 + lb;
                if (a < NA) atomicAdd((float*)outp + a, s);
            }
            // fused finish: last of the 4 x-blocks for this atile applies it
            __threadfence();
            __syncthreads();
            if (tid == 0) {
                int old = atomicAdd(&tcnt[atile], 1);
                lastF = (old == 3);
            }
            __syncthreads();
            if (lastF && tid < 128) {
                int a = rowB0 + tid;
                if (a < NA) {
                    float val = atomicAdd((float*)outp + a, 0.f);   // coherent read
                    int z = Zc[a];
                    ((float*)outp)[a] = scl[z] * (val + b3p[0]) + shf[z];
                }
            }
        }
    }
}

extern "C" void kernel_launch(void* const* d_in, const int* in_sizes, int n_in,
                              void* d_out, int out_size, void* d_ws, size_t ws_size,
                              hipStream_t stream) {
    const float* R    = (const float*)d_in[0];
    const int*   Z    = (const int*)  d_in[1];
    const int*   idx  = (const int*)  d_in[2];
    const float* Wr   = (const float*)d_in[3];
    const float* w1   = (const float*)d_in[4];
    const float* b1   = (const float*)d_in[5];
    const float* w2   = (const float*)d_in[6];
    const float* b2   = (const float*)d_in[7];
    const float* w3   = (const float*)d_in[8];
    const float* b3   = (const float*)d_in[9];
    const float* scale= (const float*)d_in[10];
    const float* shift= (const float*)d_in[11];
    float* out = (float*)d_out;
    char* ws = (char*)d_ws;

    // workspace layout (bytes)
    int*            gcur   = (int*)  (ws + 0);           // 2048 (cursors + tileCnt@+128)
    int*            tileCnt= gcur + 128;                 // 235 counters
    int*            counts = (int*)  (ws + 2048);        // 120000 -> 122048 (pad 122112)
    int*            part   = (int*)  (ws + 122112);      // 5437440 -> 5559552
    int*            plist  = (int*)  (ws + 5559552);     // 15360000 -> 20919552
    unsigned short* gmB    = (unsigned short*)(ws + 20919552);  // 23101440 -> 44020992
    unsigned short* w1T    = (unsigned short*)(ws + 44020992);  // 393216 -> 44414208
    unsigned short* w2T    = (unsigned short*)(ws + 44414208);  // 524288 -> 44938496
    unsigned short* h1B    = (unsigned short*)(ws + 44938496);  // 30801920 -> 75740416
    float*          Wpad   = (float*)(ws + 75740416);    // 2039184 -> 77779600
    float*          Rpad   = (float*)(ws + 77779600);    // 480000 -> 78259600

    // 6 graph nodes (was 7): prep(+zeros), part, csr, momcon, gemm1, gemm2(+finish)
    k_prep   <<<(PREP_TOT + 255) / 256, 256, 0, stream>>>(Wr, R, w1, w2, Wpad, Rpad,
                                                          w1T, w2T, gcur, out);
    k_part   <<<256, 256, 0, stream>>>(idx, Z, gcur, part);
    k_csr    <<<235, 256, 0, stream>>>(part, gcur, counts, plist);
    k_momcon <<<(NA + 63) / 64, 512, 0, stream>>>(Rpad, Z, Wpad, counts, plist, gmB);

    k_mfma<KP1, 1><<<dim3(NU / 128, 118), 256, 0, stream>>>(
        gmB, w1T, b1, nullptr, (void*)h1B, nullptr, nullptr, nullptr, nullptr, nullptr);
    k_mfma<NU,  2><<<dim3(NU / 128, 118), 256, 0, stream>>>(
        w2T, h1B, b2, w3, (void*)out, Z, scale, shift, b3, tileCnt);
}